// Round 12
// baseline (176.318 us; speedup 1.0000x reference)
//
#include <hip/hip_runtime.h>
#include <hip/hip_bf16.h>

#define B_ 128
#define S_ 513
#define H_ 256
#define SH_ (S_ * H_)

typedef __attribute__((ext_vector_type(8))) short short8;
typedef __attribute__((ext_vector_type(4))) float f32x4;

// Pack 8 fp32 -> 8 bf16 (RNE) via the HW packed converter.
static __device__ inline short8 pack8(float4 a, float4 b) {
    union { short8 s; __hip_bfloat162 h[4]; } u;
    u.h[0] = __float22bfloat162_rn(make_float2(a.x, a.y));
    u.h[1] = __float22bfloat162_rn(make_float2(a.z, a.w));
    u.h[2] = __float22bfloat162_rn(make_float2(b.x, b.y));
    u.h[3] = __float22bfloat162_rn(make_float2(b.z, b.w));
    return u.s;
}
static __device__ inline short8 pack8v(f32x4 a, f32x4 b) {
    union { short8 s; __hip_bfloat162 h[4]; } u;
    u.h[0] = __float22bfloat162_rn(make_float2(a[0], a[1]));
    u.h[1] = __float22bfloat162_rn(make_float2(a[2], a[3]));
    u.h[2] = __float22bfloat162_rn(make_float2(b[0], b[1]));
    u.h[3] = __float22bfloat162_rn(make_float2(b[2], b[3]));
    return u.s;
}

// WORKSPACE-FREE version. R5/R10 counter arithmetic: dur_us = 2 x 256MiB
// fillBufferAligned (~83 us, workspace re-poison) + prep + sel_gemm in
// EVERY round -- the timed window is dominated by harness workspace
// poisoning, and the MODE-1 (no d_ws) path has never been exercised.
// This round: single dispatch, d_ws untouched, no prep kernel. W is
// packed fp32->bf16 inside the pre-barrier hoist (hidden under the HBM
// stage; W = 1.3 MB, L2-hot); bias is summed (5 terms) in the epilogue.
// GEMM structure = R11 (best, 43 us): 512 thr / 8 waves x 32-d slices,
// 32-row b-major tiles, gload_lds pre-swizzled-source staging, one
// __syncthreads, pure LDS+MFMA K-loop, 2 blocks/CU.
//
// Work map (b-major): bid<2048: b=bid>>4, par=sub&1, q=sub>>1 (0..7):
// 32 s-rows, s=(par?3:4)+q*64+2r (W3/W4 by parity). bid>=2048: 12 edge
// blocks, s=e>>2 in {0,1,2}, 32 b-rows each (W0-2).
__global__ __launch_bounds__(512, 4)
void sel_gemm_kernel(const float* __restrict__ x,
                     const float* __restrict__ W,
                     const float* __restrict__ bias,
                     float* __restrict__ out) {
    __shared__ float As[32 * 256];          // 32 KB, gload_lds (linear dest)

    const int bid  = blockIdx.x;
    const int t    = threadIdx.x;
    const int lane = t & 63;
    const int w8   = t >> 6;        // 0..7 : d-slice (w8*32)
    const int lrow = lane & 15;
    const int quad = lane >> 4;

    int m_idx, rmax;
    size_t xrow0, rstride;
    if (bid < 2048) {
        const int b   = bid >> 4;
        const int sub = bid & 15;
        const int par = sub & 1;
        const int q   = sub >> 1;           // 0..7
        const int sbase = (par ? 3 : 4) + q * 64;
        m_idx   = par ? 3 : 4;
        xrow0   = (size_t)b * S_ + sbase;   // row r -> s = sbase + 2r
        rstride = 2;
        rmax    = (512 - sbase) >> 1;
        if (rmax > 31) rmax = 31;
    } else {
        const int e  = bid - 2048;          // 0..11
        const int s  = e >> 2;              // 0..2
        const int bq = e & 3;
        m_idx   = s;
        xrow0   = (size_t)(bq * 32) * S_ + s;   // row r -> b = bq*32+r
        rstride = S_;
        rmax    = 31;
    }

    // ---- 1) W-hoist: this wave's 32-d slice, all K=256, fp32 -> bf16
    // (16 short8). Issued FIRST so L2 latency + pack hide under the stage.
    // Wave reads 16 rows x 128 B contiguous per (kk,j) -> line-coalesced.
    short8 wfr[2][8];
    {
        const float* Wb = W + (size_t)m_idx * H_ * H_;
#pragma unroll
        for (int kk = 0; kk < 8; ++kk)
#pragma unroll
            for (int j = 0; j < 2; ++j) {
                const float* wrow = Wb +
                    (size_t)(w8 * 32 + j * 16 + lrow) * H_ + kk * 32 + quad * 8;
                float4 v0 = *(const float4*)wrow;
                float4 v1 = *(const float4*)(wrow + 4);
                wfr[j][kk] = pack8(v0, v1);
            }
    }

    // ---- 2) Stage x: 32 rows x 256 fp32 via gload_lds, 4 rows/wave (one
    // instruction = one full 1 KB row, wave-uniform LDS base + lane*16).
    // Per-lane GLOBAL chunk = lane^(row&7) so LDS chunk c holds global
    // chunk c^(row&7); K-loop reads apply the same XOR (<=2-way, free).
#pragma unroll
    for (int it = 0; it < 4; ++it) {
        const int row = w8 * 4 + it;        // 0..31
        int rg = row <= rmax ? row : rmax;  // clamp data; slot stays row
        const float* src = x + (xrow0 + rstride * rg) * H_
                             + ((lane ^ (row & 7)) << 2);
        __builtin_amdgcn_global_load_lds(
            (const __attribute__((address_space(1))) unsigned int*)src,
            (__attribute__((address_space(3))) unsigned int*)&As[row * 256],
            16, 0, 0);
    }

    f32x4 acc[2][2];
#pragma unroll
    for (int i = 0; i < 2; ++i)
#pragma unroll
        for (int j = 0; j < 2; ++j) {
            f32x4 z = {0.f, 0.f, 0.f, 0.f};
            acc[i][j] = z;
        }

    // ---- Pin W fragments so the loads+packs cannot sink into the K-loop.
#pragma unroll
    for (int kk = 0; kk < 8; ++kk)
#pragma unroll
        for (int j = 0; j < 2; ++j)
            asm volatile("" : "+v"(wfr[j][kk]));
    __builtin_amdgcn_sched_barrier(0);

    __syncthreads();   // vmcnt(0) drain: stage AND W-hoist complete

    // ---- 3) K-loop: 8 steps of 32. Pure LDS + register MFMA.
#pragma unroll
    for (int kk = 0; kk < 8; ++kk) {
        short8 xfr[2];
        const int g0 = kk * 8 + quad * 2;   // global 16B-chunk index
#pragma unroll
        for (int i = 0; i < 2; ++i) {
            const int r = i * 16 + lrow;
            f32x4 f0 = *(const f32x4*)&As[r * 256 + (((g0    ) ^ (r & 7)) << 2)];
            f32x4 f1 = *(const f32x4*)&As[r * 256 + (((g0 + 1) ^ (r & 7)) << 2)];
            xfr[i] = pack8v(f0, f1);
        }
#pragma unroll
        for (int j = 0; j < 2; ++j)
#pragma unroll
            for (int i = 0; i < 2; ++i)
                acc[i][j] = __builtin_amdgcn_mfma_f32_16x16x32_bf16(
                    wfr[j][kk], xfr[i], acc[i][j], 0, 0, 0);
    }

    // ---- Bias: sum of all 5 bias vectors at this d (1 KB table, L1-hot).
    f32x4 bj[2];
#pragma unroll
    for (int j = 0; j < 2; ++j) {
        const int d0 = w8 * 32 + j * 16 + quad * 4;
        f32x4 sum = {0.f, 0.f, 0.f, 0.f};
#pragma unroll
        for (int i = 0; i < 5; ++i)
            sum += *(const f32x4*)(bias + i * H_ + d0);
        bj[j] = sum;
    }

    // ---- Epilogue. A=W, B=x -> col(lane&15)=tile row, row(quad*4+reg)=d.
#pragma unroll
    for (int j = 0; j < 2; ++j) {
        const int d0 = w8 * 32 + j * 16 + quad * 4;
#pragma unroll
        for (int i = 0; i < 2; ++i) {
            const int rg = i * 16 + lrow;
            if (rg <= rmax) {
                f32x4 v = acc[i][j] + bj[j];
                *(f32x4*)(out + (xrow0 + rstride * rg) * H_ + d0) = v;
            }
        }
    }
}

extern "C" void kernel_launch(void* const* d_in, const int* in_sizes, int n_in,
                              void* d_out, int out_size, void* d_ws, size_t ws_size,
                              hipStream_t stream) {
    const float* x    = (const float*)d_in[0];
    const float* W    = (const float*)d_in[1];
    const float* bias = (const float*)d_in[2];
    float* out = (float*)d_out;

    (void)d_ws; (void)ws_size;   // workspace deliberately UNUSED this round:
                                 // testing whether the 2x256MiB re-poison
                                 // fills vanish from the timed window.

    sel_gemm_kernel<<<dim3(2048 + 12), dim3(512), 0, stream>>>(
        x, W, bias, out);
}